// Round 1
// baseline (196.990 us; speedup 1.0000x reference)
//
#include <hip/hip_runtime.h>
#include <hip/hip_bf16.h>

// FeatureInteraction: out[b, triu(i,j)] = dot(X[b,i,:], X[b,j,:])
// X: (B=4096, F=64, D=128) fp32.  out: (B, 2016) fp32.
// Memory-bound op (~160 MiB traffic). Strategy: bf16 MFMA gram per batch,
// one 256-thread block per batch, X[b] staged fp32->bf16 in swizzled LDS.

typedef __attribute__((ext_vector_type(8))) short short8;   // 8 bf16 (4 VGPRs) — MFMA A/B frag
typedef __attribute__((ext_vector_type(4))) float f32x4;    // MFMA C/D frag

// fp32 -> bf16 with round-to-nearest-even (matches hardware cvt semantics; inputs are finite)
__device__ __forceinline__ short f2bf(float f) {
    union { float f; unsigned u; } c; c.f = f;
    unsigned u = c.u;
    u += 0x7FFFu + ((u >> 16) & 1u);
    return (short)(u >> 16);
}

__global__ __launch_bounds__(256, 4)
void fi_gram_kernel(const float* __restrict__ X, float* __restrict__ out) {
    // LDS: 64 rows x 128 bf16 (256 B/row), XOR-swizzled to kill the
    // 16-way bank conflict of stride-256B ds_read_b128 (guide §6 G4).
    __shared__ __align__(16) unsigned char lds[64 * 256];

    const int b = blockIdx.x;
    const int t = threadIdx.x;
    const float* __restrict__ xb = X + (size_t)b * (64 * 128);

    // ---- stage: global fp32 -> bf16 -> swizzled LDS ----
    // 8192 floats = 1024 chunks of 8; 4 chunks/thread; each chunk = 2x dwordx4 load.
    #pragma unroll
    for (int c = 0; c < 4; ++c) {
        const int g    = t + 256 * c;          // chunk id 0..1023
        const int row  = g >> 4;               // 16 chunks per 128-float row
        const int colb = (g & 15) << 4;        // byte offset of 8-bf16 chunk in row
        f32x4 v0 = *(const f32x4*)(xb + 8 * g);
        f32x4 v1 = *(const f32x4*)(xb + 8 * g + 4);
        short8 h;
        h[0] = f2bf(v0[0]); h[1] = f2bf(v0[1]); h[2] = f2bf(v0[2]); h[3] = f2bf(v0[3]);
        h[4] = f2bf(v1[0]); h[5] = f2bf(v1[1]); h[6] = f2bf(v1[2]); h[7] = f2bf(v1[3]);
        *(short8*)(lds + row * 256 + (colb ^ ((row & 7) << 4))) = h;
    }
    __syncthreads();

    // ---- compute: wave w owns gram rows [16w, 16w+16), col-tiles jt >= w ----
    const int w  = t >> 6;        // wave id 0..3
    const int l  = t & 63;        // lane
    const int lr = l & 15;        // A row / B col within tile
    const int lk = l >> 4;        // k-group 0..3 (8 bf16 each)

    // A fragments: rows 16w+lr, k = 32*kt + 8*lk .. +7  (16B contiguous in LDS row)
    const int arow = 16 * w + lr;
    const int aswz = (arow & 7) << 4;
    short8 afrag[4];
    #pragma unroll
    for (int kt = 0; kt < 4; ++kt) {
        const int colb = 64 * kt + 16 * lk;
        afrag[kt] = *(const short8*)(lds + arow * 256 + (colb ^ aswz));
    }

    float* __restrict__ ob = out + (size_t)b * 2016;

    const int brow0 = 16 * 0 + lr; (void)brow0;
    for (int jt = w; jt < 4; ++jt) {
        const int brow = 16 * jt + lr;
        const int bswz = (brow & 7) << 4;
        f32x4 acc = {0.f, 0.f, 0.f, 0.f};
        #pragma unroll
        for (int kt = 0; kt < 4; ++kt) {
            const int colb = 64 * kt + 16 * lk;
            short8 bfrag = *(const short8*)(lds + brow * 256 + (colb ^ bswz));
            acc = __builtin_amdgcn_mfma_f32_16x16x32_bf16(afrag[kt], bfrag, acc, 0, 0, 0);
        }
        // C/D layout (m89): col = lane&15, row = (lane>>4)*4 + reg
        const int j = 16 * jt + lr;
        #pragma unroll
        for (int r = 0; r < 4; ++r) {
            const int i = 16 * w + 4 * lk + r;
            if (j > i) {
                // strict-upper row-major index: i*63 - i(i-1)/2 + (j-i-1)
                const int idx = i * 63 - (i * (i - 1)) / 2 + (j - i - 1);
                ob[idx] = acc[r];
            }
        }
    }
}

extern "C" void kernel_launch(void* const* d_in, const int* in_sizes, int n_in,
                              void* d_out, int out_size, void* d_ws, size_t ws_size,
                              hipStream_t stream) {
    const float* X = (const float*)d_in[0];
    float* out = (float*)d_out;
    const int B = in_sizes[0] / (64 * 128);   // 4096
    fi_gram_kernel<<<dim3(B), dim3(256), 0, stream>>>(X, out);
}

// Round 3
// 196.026 us; speedup vs baseline: 1.0049x; 1.0049x over previous
//
#include <hip/hip_runtime.h>
#include <hip/hip_bf16.h>

// FeatureInteraction: out[b, triu(i,j)] = dot(X[b,i,:], X[b,j,:])
// X: (B=4096, F=64, D=128) fp32.  out: (B, 2016) fp32.
// Traffic-optimal: read X once (134 MB), write out once (33 MB) -> ~27 us floor.
// bf16 MFMA gram per batch; one 256-thread block per batch; X[b] staged
// fp32->bf16 into XOR-swizzled LDS; 10 upper 16x16 tiles split 3/3/2/2 per wave.

typedef __attribute__((ext_vector_type(8))) short bf16x8;   // 8 bf16 — MFMA A/B frag
typedef __attribute__((ext_vector_type(4))) short bf16x4;   // 4 bf16 (8 B)
typedef __attribute__((ext_vector_type(4))) float f32x4;    // 16 B load / MFMA C frag

// fp32 -> bf16 round-to-nearest-even
__device__ __forceinline__ short f2bf(float f) {
    union { float f; unsigned u; } c; c.f = f;
    unsigned u = c.u;
    u += 0x7FFFu + ((u >> 16) & 1u);
    return (short)(u >> 16);
}

__global__ __launch_bounds__(256, 4)
void fi_gram_kernel(const float* __restrict__ X, float* __restrict__ out) {
    // 64 rows x 128 bf16 (256 B/row); XOR swizzle kills the 16-way bank
    // conflict of stride-256B ds_read_b128 (guide §6 G4).
    __shared__ __align__(16) unsigned char lds[64 * 256];

    const int b = blockIdx.x;
    const int t = threadIdx.x;
    const float* __restrict__ xb = X + (size_t)b * (64 * 128);

    // ---- stage: fully-coalesced 16B-unit loads (lane stride 16 B) ----
    // 8192 floats = 2048 f32x4 units; thread t owns units t + 256k, k=0..7.
    f32x4 v[8];
    #pragma unroll
    for (int k = 0; k < 8; ++k)
        v[k] = *(const f32x4*)(xb + 4 * (t + 256 * k));   // all loads issue first

    #pragma unroll
    for (int k = 0; k < 8; ++k) {
        const int u    = t + 256 * k;
        const int row  = u >> 5;                 // 32 units per 128-float row
        const int colb = (u & 31) << 3;          // byte offset of 4-bf16 unit
        bf16x4 h;
        h[0] = f2bf(v[k][0]); h[1] = f2bf(v[k][1]);
        h[2] = f2bf(v[k][2]); h[3] = f2bf(v[k][3]);
        *(bf16x4*)(lds + row * 256 + (colb ^ ((row & 7) << 4))) = h;
    }
    __syncthreads();

    // ---- compute: 10 upper 16x16 tiles of the 64x64 gram, 3/3/2/2 per wave ----
    const int w  = t >> 6;        // wave id 0..3
    const int l  = t & 63;        // lane
    const int lr = l & 15;        // row/col within 16-tile
    const int lk = l >> 4;        // k-group 0..3 (8 bf16 each)

    // packed tile tables: tile s -> (row-tile, col-tile)
    const int start = (0x8630 >> (4 * w)) & 15;   // {0,3,6,8}
    const int cnt   = (0x2233 >> (4 * w)) & 15;   // {3,3,2,2}

    float* __restrict__ ob = out + (size_t)b * 2016;

    for (int s = 0; s < cnt; ++s) {
        const int ti = start + s;
        const int it = (0xE9500 >> (2 * ti)) & 3;   // 0,0,0,0,1,1,1,2,2,3
        const int jt = (0xFB9E4 >> (2 * ti)) & 3;   // 0,1,2,3,1,2,3,2,3,3

        const int arow = 16 * it + lr, aswz = (arow & 7) << 4;
        const int brow = 16 * jt + lr, bswz = (brow & 7) << 4;
        f32x4 acc = {0.f, 0.f, 0.f, 0.f};
        #pragma unroll
        for (int kt = 0; kt < 4; ++kt) {
            const int colb = 64 * kt + 16 * lk;
            bf16x8 af = *(const bf16x8*)(lds + arow * 256 + (colb ^ aswz));
            bf16x8 bf = *(const bf16x8*)(lds + brow * 256 + (colb ^ bswz));
            acc = __builtin_amdgcn_mfma_f32_16x16x32_bf16(af, bf, acc, 0, 0, 0);
        }
        // C/D layout (m89): col = lane&15, row = (lane>>4)*4 + reg
        const int j = 16 * jt + lr;
        #pragma unroll
        for (int r = 0; r < 4; ++r) {
            const int i = 16 * it + 4 * lk + r;
            if (j > i) {
                const int idx = i * 63 - (i * (i - 1)) / 2 + (j - i - 1);
                ob[idx] = acc[r];
            }
        }
    }
}

extern "C" void kernel_launch(void* const* d_in, const int* in_sizes, int n_in,
                              void* d_out, int out_size, void* d_ws, size_t ws_size,
                              hipStream_t stream) {
    const float* X = (const float*)d_in[0];
    float* out = (float*)d_out;
    const int B = in_sizes[0] / (64 * 128);   // 4096
    fi_gram_kernel<<<dim3(B), dim3(256), 0, stream>>>(X, out);
}